// Round 8
// baseline (132.896 us; speedup 1.0000x reference)
//
#include <hip/hip_runtime.h>
#include <hip/hip_bf16.h>

#define NBS 8
#define NT 32
#define NF 128
#define NDIN 64
#define NNH 8
#define NDOUT 64

typedef __bf16 bf16_t;
typedef __bf16 bf16x8 __attribute__((ext_vector_type(8)));
typedef float f32x4 __attribute__((ext_vector_type(4)));

// ---------------- kernel 1: q/k projection ----------------
// One wave per (t,f): q[b,he] = sum_d X[b,f,t,d] * Wq[t,f,d,he], all 8 b at once.
// Wq/Wk/X each read exactly once from HBM -> ~46MB -> memory-bound ~8us.
__global__ __launch_bounds__(256, 4)
void qk_project_kernel(const float* __restrict__ X,
                       const float* __restrict__ Wq,
                       const float* __restrict__ Wk,
                       float* __restrict__ q_ws,
                       float* __restrict__ k_ws)
{
    __shared__ float lx[4][8][64];
    const int w = threadIdx.x >> 6, lane = threadIdx.x & 63;
    const int gw = blockIdx.x * 4 + w;
    const int t = gw >> 7, f = gw & 127;

    {
        const int b = lane >> 3, d8 = (lane & 7) << 3;
        const float* src = &X[(((size_t)b * NF + f) * NT + t) * NDIN + d8];
        const float4 v0 = *(const float4*)src;
        const float4 v1 = *(const float4*)(src + 4);
        *(float4*)&lx[w][b][d8]     = v0;
        *(float4*)&lx[w][b][d8 + 4] = v1;
    }
    __syncthreads();

    const int dq = lane >> 4, he = lane & 15;
    const float* wq = Wq + ((size_t)t * NF + f) * (NDIN * 16);
    const float* wk = Wk + ((size_t)t * NF + f) * (NDIN * 16);
    float qa[8] = {0,0,0,0,0,0,0,0}, ka[8] = {0,0,0,0,0,0,0,0};
    for (int d0 = 0; d0 < NDIN; d0 += 4) {
        const int d = d0 + dq;
        const float wqv = wq[d * 16 + he];
        const float wkv = wk[d * 16 + he];
#pragma unroll
        for (int b = 0; b < 8; ++b) {
            const float x = lx[w][b][d];
            qa[b] = fmaf(x, wqv, qa[b]);
            ka[b] = fmaf(x, wkv, ka[b]);
        }
    }
#pragma unroll
    for (int b = 0; b < 8; ++b) {
        qa[b] += __shfl_xor(qa[b], 16); qa[b] += __shfl_xor(qa[b], 32);
        ka[b] += __shfl_xor(ka[b], 16); ka[b] += __shfl_xor(ka[b], 32);
    }
#pragma unroll
    for (int bb = 0; bb < 2; ++bb) {
        const int b = dq + bb * 4;
        q_ws[(((size_t)b * NT + t) * 16 + he) * NF + f] = qa[b];
        k_ws[(((size_t)b * NT + t) * 16 + he) * NF + f] = ka[b];
    }
}

// ---------------- kernel 2: attention + output GEMMs ----------------
// Grid 512 = (b, t, hg): block does heads hg*4..hg*4+3 for all 128 f.
// 512 thr = 8 waves, wave w = row-tile rt (r7's verified per-wave math).
// LDS 62992 -> 2 blocks/CU -> 4 waves/SIMD (2x r7 occupancy).
// XT/WT XOR-swizzled (chunk ^= row) -> 2-way banks (was 8-way with +pad).
// Two hg blocks combine via atomicAdd f32 (2 commutative adds -> deterministic);
// d_out zeroed via hipMemsetAsync each call.
__global__ __launch_bounds__(512, 4)
void spatial_attn_kernel(const float* __restrict__ X,
                         const float* __restrict__ q_ws,
                         const float* __restrict__ k_ws,
                         const float* __restrict__ Wkey,
                         const float* __restrict__ U,
                         const float* __restrict__ AC,
                         const float* __restrict__ Alpha,
                         const float* __restrict__ Wo,
                         const float* __restrict__ Bias,
                         float* __restrict__ Out)
{
    const int blk  = blockIdx.x;
    const int b    = blk & 7;          // 8 consecutive blocks share (t,hg): Wo/U slices L2-hot
    const int tq   = blk >> 3;
    const int hg   = tq & 1;
    const int t    = tq >> 1;
    const int tid  = threadIdx.x;
    const int w    = tid >> 6;
    const int lane = tid & 63;
    const int cq   = lane & 15;
    const int rq   = lane >> 4;
    const int rt   = w;                // row tile 0..7
    const int frow = 16 * rt + cq;

    // LDS carve: 62992 B
    __shared__ __align__(16) unsigned char smem[62992];
    bf16_t* XTs        = (bf16_t*)smem;                      // 16384: (d,l) -> d*128 + (((l>>3)^(d&15))<<3) + (l&7)
    float4 (*kv)[136]  = (float4 (*)[136])(smem + 16384);    // 8704: {k0,k1,u0,u1}(th,l), slot 17*(l>>4)+(l&15)
    float2 (*qls)[128] = (float2 (*)[128])(smem + 25088);    // 4096: {q0,q1}(th,f)
    float*  acs        = (float*)(smem + 29184);             // 16
    bf16_t* WTs        = (bf16_t*)(smem + 29200);            // 16384: buf*4096 + o*64 + (((d>>3)^(o&7))<<3) + (d&7)
    bf16_t (*Vscr)[16][68] = (bf16_t (*)[16][68])(smem + 45584); // 17408

    // ---- stage XT (X^T bf16, XOR-swizzled) ----
#pragma unroll
    for (int r = 0; r < 4; ++r) {
        const int idx = tid + r * 512;
        const int f = idx >> 4, d4 = (idx & 15) << 2;
        const float4 v = *(const float4*)&X[(((size_t)b * NF + f) * NT + t) * NDIN + d4];
        float vv[4]; vv[0] = v.x; vv[1] = v.y; vv[2] = v.z; vv[3] = v.w;
#pragma unroll
        for (int i = 0; i < 4; ++i) {
            const int d = d4 + i;
            XTs[d * 128 + (((f >> 3) ^ (d & 15)) << 3) + (f & 7)] = (bf16_t)vv[i];
        }
    }
    // ---- stage kv, qls (this block's 4 heads), acs ----
    {
        const int hh = tid >> 7, l = tid & 127;
        const int h = hg * 4 + hh;
        const size_t qkb = ((size_t)b * NT + t) * 16;
        const float k0 = k_ws[(qkb + 2 * h + 0) * NF + l];
        const float k1 = k_ws[(qkb + 2 * h + 1) * NF + l];
        const float2 u01 = *(const float2*)&U[((size_t)t * NF + l) * 2];
        kv[hh][17 * (l >> 4) + (l & 15)] = make_float4(k0, k1, u01.x, u01.y);
        const float q0 = q_ws[(qkb + 2 * h + 0) * NF + l];
        const float q1 = q_ws[(qkb + 2 * h + 1) * NF + l];
        qls[hh][l] = make_float2(q0, q1);
    }
    if (tid < 4) acs[tid] = AC[t * NNH + hg * 4 + tid];
    // ---- stage WT for first head into buf 0 ----
#pragma unroll
    for (int r = 0; r < 2; ++r) {
        const int idx = tid + r * 512;
        const int dd = idx >> 4, o4 = (idx & 15) << 2;
        const float4 v = *(const float4*)&Wo[((size_t)t * 512 + (hg * 4) * 64 + dd) * NDOUT + o4];
        float vv[4]; vv[0] = v.x; vv[1] = v.y; vv[2] = v.z; vv[3] = v.w;
#pragma unroll
        for (int i = 0; i < 4; ++i) {
            const int o = o4 + i;
            WTs[o * 64 + (((dd >> 3) ^ (o & 7)) << 3) + (dd & 7)] = (bf16_t)vv[i];
        }
    }

    const float alpha_t = Alpha[t];
    const float wk00 = Wkey[t * 4 + 0], wk01 = Wkey[t * 4 + 1];
    const float wk10 = Wkey[t * 4 + 2], wk11 = Wkey[t * 4 + 3];

    __syncthreads();   // staging complete

    f32x4 oacc[4] = { {0.f,0.f,0.f,0.f}, {0.f,0.f,0.f,0.f}, {0.f,0.f,0.f,0.f}, {0.f,0.f,0.f,0.f} };

#pragma unroll 1
    for (int th = 0; th < 4; ++th) {
        // stage WT for th+1 into the other buffer (disjoint from this head's reads)
        if (th < 3) {
            const int hn = hg * 4 + th + 1;
            const int bn = ((th + 1) & 1) * 4096;
#pragma unroll
            for (int r = 0; r < 2; ++r) {
                const int idx = tid + r * 512;
                const int dd = idx >> 4, o4 = (idx & 15) << 2;
                const float4 v = *(const float4*)&Wo[((size_t)t * 512 + hn * 64 + dd) * NDOUT + o4];
                float vv[4]; vv[0] = v.x; vv[1] = v.y; vv[2] = v.z; vv[3] = v.w;
#pragma unroll
                for (int i = 0; i < 4; ++i) {
                    const int o = o4 + i;
                    WTs[bn + o * 64 + (((dd >> 3) ^ (o & 7)) << 3) + (dd & 7)] = (bf16_t)vv[i];
                }
            }
        }
        const int buf = (th & 1) * 4096;
        const float2 qq = qls[th][frow];
        const float4 kk = kv[th][17 * (frow >> 4) + (frow & 15)];
        const float q0 = qq.x, q1 = qq.y, kf0 = kk.x, kf1 = kk.y;
        const float v1 = 2.f * alpha_t * acs[th];
        const float c0 = (q0 - alpha_t) * wk00 + (q1 + v1) * wk10;
        const float c1 = (q0 - alpha_t) * wk01 + (q1 + v1) * wk11;

        // scores in A-frag layout: sc[kt][j] = S[frow][kt*32 + rq*8 + j]
        float sc[4][8];
        float rowmax = -3.0e38f;
#pragma unroll
        for (int kt = 0; kt < 4; ++kt) {
            const int s  = kt * 2 + (rq >> 1);
            const int i0 = (rq & 1) << 3;
            const float4* kvp = &kv[th][17 * s + i0];
            float del = (float)(kt * 32 + rq * 8 - frow);
#pragma unroll
            for (int j = 0; j < 8; ++j) {
                const float4 kj = kvp[j];
                const float sv = q0 * kj.x + q1 * kj.y + kf0 * kj.z + kf1 * kj.w
                               + (c0 * del + c1) * del;
                sc[kt][j] = sv;
                rowmax = fmaxf(rowmax, sv);
                del += 1.f;
            }
        }
        rowmax = fmaxf(rowmax, __shfl_xor(rowmax, 16));
        rowmax = fmaxf(rowmax, __shfl_xor(rowmax, 32));
        float sum = 0.f;
#pragma unroll
        for (int kt = 0; kt < 4; ++kt)
#pragma unroll
            for (int j = 0; j < 8; ++j) {
                sc[kt][j] = __expf(sc[kt][j] - rowmax);
                sum += sc[kt][j];
            }
        sum += __shfl_xor(sum, 16);
        sum += __shfl_xor(sum, 32);
        const float rinv = 1.f / sum;

        // GEMM1: V[16x64] = P[16x128] @ X[128x64]; P normalized pre-MFMA
        f32x4 vacc[4] = { {0.f,0.f,0.f,0.f}, {0.f,0.f,0.f,0.f}, {0.f,0.f,0.f,0.f}, {0.f,0.f,0.f,0.f} };
#pragma unroll
        for (int kt = 0; kt < 4; ++kt) {
            bf16x8 pf;
#pragma unroll
            for (int j = 0; j < 8; ++j) pf[j] = (bf16_t)(sc[kt][j] * rinv);
#pragma unroll
            for (int ct = 0; ct < 4; ++ct) {
                const bf16x8 bb = *(const bf16x8*)&XTs[(ct * 16 + cq) * 128 + (((kt * 4 + rq) ^ cq) << 3)];
                vacc[ct] = __builtin_amdgcn_mfma_f32_16x16x32_bf16(pf, bb, vacc[ct], 0, 0, 0);
            }
        }
        // V C-frags -> private wave scratch (intra-wave dep only)
#pragma unroll
        for (int ct = 0; ct < 4; ++ct)
#pragma unroll
            for (int rr = 0; rr < 4; ++rr)
                Vscr[w][rq * 4 + rr][ct * 16 + cq] = (bf16_t)vacc[ct][rr];

        // GEMM2: oacc += V[16x64] @ W_h[64x64]
#pragma unroll
        for (int kt = 0; kt < 2; ++kt) {
            const bf16x8 a = *(const bf16x8*)&Vscr[w][cq][kt * 32 + rq * 8];
#pragma unroll
            for (int ct = 0; ct < 4; ++ct) {
                const bf16x8 bw = *(const bf16x8*)&WTs[buf + (ct * 16 + cq) * 64 + (((kt * 4 + rq) ^ (cq & 7)) << 3)];
                oacc[ct] = __builtin_amdgcn_mfma_f32_16x16x32_bf16(a, bw, oacc[ct], 0, 0, 0);
            }
        }
        __syncthreads();   // next head's WT buffer ready; this buffer free for th+2
    }

    // ---- epilogue: atomic combine of the two hg partials; hg0 carries bias ----
#pragma unroll
    for (int ct = 0; ct < 4; ++ct) {
#pragma unroll
        for (int rr = 0; rr < 4; ++rr) {
            const int f = 16 * rt + rq * 4 + rr;
            const int o = ct * 16 + cq;
            float val = oacc[ct][rr];
            if (hg == 0) val += Bias[((size_t)f * NT + t) * NDOUT + o];
            atomicAdd(&Out[(((size_t)b * NF + f) * NT + t) * NDOUT + o], val);
        }
    }
}

extern "C" void kernel_launch(void* const* d_in, const int* in_sizes, int n_in,
                              void* d_out, int out_size, void* d_ws, size_t ws_size,
                              hipStream_t stream) {
    (void)in_sizes; (void)n_in; (void)ws_size;
    const float* X    = (const float*)d_in[0];
    const float* Wq   = (const float*)d_in[1];
    const float* Wk   = (const float*)d_in[2];
    const float* Wkey = (const float*)d_in[3];
    const float* U    = (const float*)d_in[4];
    const float* AC   = (const float*)d_in[5];
    const float* Al   = (const float*)d_in[6];
    // d_in[7] = R is analytic (delta^2, delta), folded into score formula
    const float* Wo   = (const float*)d_in[8];
    const float* Bias = (const float*)d_in[9];

    float* q_ws = (float*)d_ws;                       // 2 MB
    float* k_ws = q_ws + (size_t)NBS * NT * 16 * NF;  // 2 MB

    hipMemsetAsync(d_out, 0, (size_t)out_size * sizeof(float), stream);
    qk_project_kernel<<<dim3(NT * NF / 4), dim3(256), 0, stream>>>(X, Wq, Wk, q_ws, k_ws);
    spatial_attn_kernel<<<dim3(NBS * NT * 2), dim3(512), 0, stream>>>(
        X, q_ws, k_ws, Wkey, U, AC, Al, Wo, Bias, (float*)d_out);
}

// Round 9
// 76.954 us; speedup vs baseline: 1.7269x; 1.7269x over previous
//
#include <hip/hip_runtime.h>
#include <hip/hip_bf16.h>

#define NBS 8
#define NT 32
#define NF 128
#define NDIN 64
#define NNH 8
#define NDOUT 64

typedef __bf16 bf16_t;
typedef __bf16 bf16x8 __attribute__((ext_vector_type(8)));
typedef float f32x4 __attribute__((ext_vector_type(4)));

// ---------------- kernel 1: q/k projection ----------------
// One wave per (t,f): q[b,he] = sum_d X[b,f,t,d] * Wq[t,f,d,he], all 8 b at once.
// Wq/Wk/X each read exactly once from HBM -> ~46MB -> memory-bound ~8us.
__global__ __launch_bounds__(256, 4)
void qk_project_kernel(const float* __restrict__ X,
                       const float* __restrict__ Wq,
                       const float* __restrict__ Wk,
                       float* __restrict__ q_ws,
                       float* __restrict__ k_ws)
{
    __shared__ float lx[4][8][64];
    const int w = threadIdx.x >> 6, lane = threadIdx.x & 63;
    const int gw = blockIdx.x * 4 + w;
    const int t = gw >> 7, f = gw & 127;

    {
        const int b = lane >> 3, d8 = (lane & 7) << 3;
        const float* src = &X[(((size_t)b * NF + f) * NT + t) * NDIN + d8];
        const float4 v0 = *(const float4*)src;
        const float4 v1 = *(const float4*)(src + 4);
        *(float4*)&lx[w][b][d8]     = v0;
        *(float4*)&lx[w][b][d8 + 4] = v1;
    }
    __syncthreads();

    const int dq = lane >> 4, he = lane & 15;
    const float* wq = Wq + ((size_t)t * NF + f) * (NDIN * 16);
    const float* wk = Wk + ((size_t)t * NF + f) * (NDIN * 16);
    float qa[8] = {0,0,0,0,0,0,0,0}, ka[8] = {0,0,0,0,0,0,0,0};
    for (int d0 = 0; d0 < NDIN; d0 += 4) {
        const int d = d0 + dq;
        const float wqv = wq[d * 16 + he];
        const float wkv = wk[d * 16 + he];
#pragma unroll
        for (int b = 0; b < 8; ++b) {
            const float x = lx[w][b][d];
            qa[b] = fmaf(x, wqv, qa[b]);
            ka[b] = fmaf(x, wkv, ka[b]);
        }
    }
#pragma unroll
    for (int b = 0; b < 8; ++b) {
        qa[b] += __shfl_xor(qa[b], 16); qa[b] += __shfl_xor(qa[b], 32);
        ka[b] += __shfl_xor(ka[b], 16); ka[b] += __shfl_xor(ka[b], 32);
    }
#pragma unroll
    for (int bb = 0; bb < 2; ++bb) {
        const int b = dq + bb * 4;
        q_ws[(((size_t)b * NT + t) * 16 + he) * NF + f] = qa[b];
        k_ws[(((size_t)b * NT + t) * 16 + he) * NF + f] = ka[b];
    }
}

// ---------------- kernel 2: attention + output GEMMs ----------------
// Grid 512 = (b, t, hg): block does heads hg*4..hg*4+3 for all 128 f.
// 512 thr = 8 waves, wave w = row-tile rt. LDS 62992 -> 2 blocks/CU at
// <=128 VGPR -> 4 waves/SIMD. Two hg blocks combine via atomicAdd (2
// commutative adds -> deterministic); d_out zeroed via hipMemsetAsync.
// LAUNCH BOUNDS RULE (r4/r5/r8 evidence): second arg >=4 (or waves_per_eu(4))
// forces the 64-arch-VGPR bucket -> massive scratch spills. (512,2) is the
// proven bound: compiler allocates ~128, runtime still reaches 2 blocks/CU
// from actual VGPR/LDS usage.
__global__ __launch_bounds__(512, 2)
void spatial_attn_kernel(const float* __restrict__ X,
                         const float* __restrict__ q_ws,
                         const float* __restrict__ k_ws,
                         const float* __restrict__ Wkey,
                         const float* __restrict__ U,
                         const float* __restrict__ AC,
                         const float* __restrict__ Alpha,
                         const float* __restrict__ Wo,
                         const float* __restrict__ Bias,
                         float* __restrict__ Out)
{
    const int blk  = blockIdx.x;
    const int b    = blk & 7;          // 8 consecutive blocks share (t,hg): Wo/U slices L2-hot
    const int tq   = blk >> 3;
    const int hg   = tq & 1;
    const int t    = tq >> 1;
    const int tid  = threadIdx.x;
    const int w    = tid >> 6;
    const int lane = tid & 63;
    const int cq   = lane & 15;
    const int rq   = lane >> 4;
    const int rt   = w;                // row tile 0..7
    const int frow = 16 * rt + cq;

    // LDS carve: 62992 B
    __shared__ __align__(16) unsigned char smem[62992];
    bf16_t* XTs        = (bf16_t*)smem;                      // 16384: (d,l) -> d*128 + (((l>>3)^(d&15))<<3) + (l&7)
    float4 (*kv)[136]  = (float4 (*)[136])(smem + 16384);    // 8704: {k0,k1,u0,u1}(th,l), slot 17*(l>>4)+(l&15)
    float2 (*qls)[128] = (float2 (*)[128])(smem + 25088);    // 4096: {q0,q1}(th,f)
    float*  acs        = (float*)(smem + 29184);             // 16
    bf16_t* WTs        = (bf16_t*)(smem + 29200);            // 16384: buf*4096 + o*64 + (((d>>3)^(o&7))<<3) + (d&7)
    bf16_t (*Vscr)[16][68] = (bf16_t (*)[16][68])(smem + 45584); // 17408

    // ---- stage XT (X^T bf16, XOR-swizzled) ----
#pragma unroll
    for (int r = 0; r < 4; ++r) {
        const int idx = tid + r * 512;
        const int f = idx >> 4, d4 = (idx & 15) << 2;
        const float4 v = *(const float4*)&X[(((size_t)b * NF + f) * NT + t) * NDIN + d4];
        float vv[4]; vv[0] = v.x; vv[1] = v.y; vv[2] = v.z; vv[3] = v.w;
#pragma unroll
        for (int i = 0; i < 4; ++i) {
            const int d = d4 + i;
            XTs[d * 128 + (((f >> 3) ^ (d & 15)) << 3) + (f & 7)] = (bf16_t)vv[i];
        }
    }
    // ---- stage kv, qls (this block's 4 heads), acs ----
    {
        const int hh = tid >> 7, l = tid & 127;
        const int h = hg * 4 + hh;
        const size_t qkb = ((size_t)b * NT + t) * 16;
        const float k0 = k_ws[(qkb + 2 * h + 0) * NF + l];
        const float k1 = k_ws[(qkb + 2 * h + 1) * NF + l];
        const float2 u01 = *(const float2*)&U[((size_t)t * NF + l) * 2];
        kv[hh][17 * (l >> 4) + (l & 15)] = make_float4(k0, k1, u01.x, u01.y);
        const float q0 = q_ws[(qkb + 2 * h + 0) * NF + l];
        const float q1 = q_ws[(qkb + 2 * h + 1) * NF + l];
        qls[hh][l] = make_float2(q0, q1);
    }
    if (tid < 4) acs[tid] = AC[t * NNH + hg * 4 + tid];
    // ---- stage WT for first head into buf 0 ----
#pragma unroll
    for (int r = 0; r < 2; ++r) {
        const int idx = tid + r * 512;
        const int dd = idx >> 4, o4 = (idx & 15) << 2;
        const float4 v = *(const float4*)&Wo[((size_t)t * 512 + (hg * 4) * 64 + dd) * NDOUT + o4];
        float vv[4]; vv[0] = v.x; vv[1] = v.y; vv[2] = v.z; vv[3] = v.w;
#pragma unroll
        for (int i = 0; i < 4; ++i) {
            const int o = o4 + i;
            WTs[o * 64 + (((dd >> 3) ^ (o & 7)) << 3) + (dd & 7)] = (bf16_t)vv[i];
        }
    }

    const float alpha_t = Alpha[t];
    const float wk00 = Wkey[t * 4 + 0], wk01 = Wkey[t * 4 + 1];
    const float wk10 = Wkey[t * 4 + 2], wk11 = Wkey[t * 4 + 3];

    __syncthreads();   // staging complete

    f32x4 oacc[4] = { {0.f,0.f,0.f,0.f}, {0.f,0.f,0.f,0.f}, {0.f,0.f,0.f,0.f}, {0.f,0.f,0.f,0.f} };

#pragma unroll 1
    for (int th = 0; th < 4; ++th) {
        // stage WT for th+1 into the other buffer (disjoint from this head's reads)
        if (th < 3) {
            const int hn = hg * 4 + th + 1;
            const int bn = ((th + 1) & 1) * 4096;
#pragma unroll
            for (int r = 0; r < 2; ++r) {
                const int idx = tid + r * 512;
                const int dd = idx >> 4, o4 = (idx & 15) << 2;
                const float4 v = *(const float4*)&Wo[((size_t)t * 512 + hn * 64 + dd) * NDOUT + o4];
                float vv[4]; vv[0] = v.x; vv[1] = v.y; vv[2] = v.z; vv[3] = v.w;
#pragma unroll
                for (int i = 0; i < 4; ++i) {
                    const int o = o4 + i;
                    WTs[bn + o * 64 + (((dd >> 3) ^ (o & 7)) << 3) + (dd & 7)] = (bf16_t)vv[i];
                }
            }
        }
        const int buf = (th & 1) * 4096;
        const float2 qq = qls[th][frow];
        const float4 kk = kv[th][17 * (frow >> 4) + (frow & 15)];
        const float q0 = qq.x, q1 = qq.y, kf0 = kk.x, kf1 = kk.y;
        const float v1 = 2.f * alpha_t * acs[th];
        const float c0 = (q0 - alpha_t) * wk00 + (q1 + v1) * wk10;
        const float c1 = (q0 - alpha_t) * wk01 + (q1 + v1) * wk11;

        // scores in A-frag layout: sc[kt][j] = S[frow][kt*32 + rq*8 + j]
        float sc[4][8];
        float rowmax = -3.0e38f;
#pragma unroll
        for (int kt = 0; kt < 4; ++kt) {
            const int s  = kt * 2 + (rq >> 1);
            const int i0 = (rq & 1) << 3;
            const float4* kvp = &kv[th][17 * s + i0];
            float del = (float)(kt * 32 + rq * 8 - frow);
#pragma unroll
            for (int j = 0; j < 8; ++j) {
                const float4 kj = kvp[j];
                const float sv = q0 * kj.x + q1 * kj.y + kf0 * kj.z + kf1 * kj.w
                               + (c0 * del + c1) * del;
                sc[kt][j] = sv;
                rowmax = fmaxf(rowmax, sv);
                del += 1.f;
            }
        }
        rowmax = fmaxf(rowmax, __shfl_xor(rowmax, 16));
        rowmax = fmaxf(rowmax, __shfl_xor(rowmax, 32));
        float sum = 0.f;
#pragma unroll
        for (int kt = 0; kt < 4; ++kt)
#pragma unroll
            for (int j = 0; j < 8; ++j) {
                sc[kt][j] = __expf(sc[kt][j] - rowmax);
                sum += sc[kt][j];
            }
        sum += __shfl_xor(sum, 16);
        sum += __shfl_xor(sum, 32);
        const float rinv = 1.f / sum;

        // GEMM1: V[16x64] = P[16x128] @ X[128x64]; P normalized pre-MFMA
        f32x4 vacc[4] = { {0.f,0.f,0.f,0.f}, {0.f,0.f,0.f,0.f}, {0.f,0.f,0.f,0.f}, {0.f,0.f,0.f,0.f} };
#pragma unroll
        for (int kt = 0; kt < 4; ++kt) {
            bf16x8 pf;
#pragma unroll
            for (int j = 0; j < 8; ++j) pf[j] = (bf16_t)(sc[kt][j] * rinv);
#pragma unroll
            for (int ct = 0; ct < 4; ++ct) {
                const bf16x8 bb = *(const bf16x8*)&XTs[(ct * 16 + cq) * 128 + (((kt * 4 + rq) ^ cq) << 3)];
                vacc[ct] = __builtin_amdgcn_mfma_f32_16x16x32_bf16(pf, bb, vacc[ct], 0, 0, 0);
            }
        }
        // V C-frags -> private wave scratch (intra-wave dep only)
#pragma unroll
        for (int ct = 0; ct < 4; ++ct)
#pragma unroll
            for (int rr = 0; rr < 4; ++rr)
                Vscr[w][rq * 4 + rr][ct * 16 + cq] = (bf16_t)vacc[ct][rr];

        // GEMM2: oacc += V[16x64] @ W_h[64x64]
#pragma unroll
        for (int kt = 0; kt < 2; ++kt) {
            const bf16x8 a = *(const bf16x8*)&Vscr[w][cq][kt * 32 + rq * 8];
#pragma unroll
            for (int ct = 0; ct < 4; ++ct) {
                const bf16x8 bw = *(const bf16x8*)&WTs[buf + (ct * 16 + cq) * 64 + (((kt * 4 + rq) ^ (cq & 7)) << 3)];
                oacc[ct] = __builtin_amdgcn_mfma_f32_16x16x32_bf16(a, bw, oacc[ct], 0, 0, 0);
            }
        }
        __syncthreads();   // next head's WT buffer ready; this buffer free for th+2
    }

    // ---- epilogue: atomic combine of the two hg partials; hg0 carries bias ----
#pragma unroll
    for (int ct = 0; ct < 4; ++ct) {
#pragma unroll
        for (int rr = 0; rr < 4; ++rr) {
            const int f = 16 * rt + rq * 4 + rr;
            const int o = ct * 16 + cq;
            float val = oacc[ct][rr];
            if (hg == 0) val += Bias[((size_t)f * NT + t) * NDOUT + o];
            atomicAdd(&Out[(((size_t)b * NF + f) * NT + t) * NDOUT + o], val);
        }
    }
}

extern "C" void kernel_launch(void* const* d_in, const int* in_sizes, int n_in,
                              void* d_out, int out_size, void* d_ws, size_t ws_size,
                              hipStream_t stream) {
    (void)in_sizes; (void)n_in; (void)ws_size;
    const float* X    = (const float*)d_in[0];
    const float* Wq   = (const float*)d_in[1];
    const float* Wk   = (const float*)d_in[2];
    const float* Wkey = (const float*)d_in[3];
    const float* U    = (const float*)d_in[4];
    const float* AC   = (const float*)d_in[5];
    const float* Al   = (const float*)d_in[6];
    // d_in[7] = R is analytic (delta^2, delta), folded into score formula
    const float* Wo   = (const float*)d_in[8];
    const float* Bias = (const float*)d_in[9];

    float* q_ws = (float*)d_ws;                       // 2 MB
    float* k_ws = q_ws + (size_t)NBS * NT * 16 * NF;  // 2 MB

    hipMemsetAsync(d_out, 0, (size_t)out_size * sizeof(float), stream);
    qk_project_kernel<<<dim3(NT * NF / 4), dim3(256), 0, stream>>>(X, Wq, Wk, q_ws, k_ws);
    spatial_attn_kernel<<<dim3(NBS * NT * 2), dim3(512), 0, stream>>>(
        X, q_ws, k_ws, Wkey, U, AC, Al, Wo, Bias, (float*)d_out);
}